// Round 1
// baseline (3962.880 us; speedup 1.0000x reference)
//
#include <hip/hip_runtime.h>
#include <hip/hip_bf16.h>
#include <math.h>

#define L_ 6
#define H_ 16
#define D_ 1024
#define V_ 50257
#define B_ 2
#define T_ 1024
#define M_ (B_*T_)

typedef unsigned short u16;
typedef __attribute__((ext_vector_type(8))) __bf16 bf16x8;
typedef __attribute__((ext_vector_type(4))) float f32x4;

__device__ __forceinline__ u16 f2bf(float x){
  union { __hip_bfloat16 h; u16 u; } c;
  c.h = __float2bfloat16(x);
  return c.u;
}

__device__ __forceinline__ void gload_lds16(const void* g, void* l){
  __builtin_amdgcn_global_load_lds(
      (__attribute__((address_space(1))) void*)(const_cast<void*>(g)),
      (__attribute__((address_space(3))) void*)l, 16, 0, 0);
}

// ---------------- fp32 -> bf16 weight conversion ----------------
__global__ void cvt_bf16x4(const float4* __restrict__ in, ushort4* __restrict__ out, int n4){
  int i = blockIdx.x*256 + threadIdx.x;
  if (i < n4){
    float4 v = in[i];
    ushort4 o;
    o.x = f2bf(v.x); o.y = f2bf(v.y); o.z = f2bf(v.z); o.w = f2bf(v.w);
    out[i] = o;
  }
}

// ---------------- embedding ----------------
__global__ void embed_k(const int* __restrict__ idx, const float* __restrict__ wte,
                        const float* __restrict__ wpe, float* __restrict__ xb){
  int m = blockIdx.x;
  int t = m % T_;
  int tok = idx[m];
  const float* w = wte + (size_t)tok*D_;
  const float* p = wpe + (size_t)t*D_;
  float* o = xb + (size_t)m*D_;
  for (int d = threadIdx.x; d < D_; d += 256) o[d] = w[d] + p[d];
}

// ---------------- layernorm (fp32 in, bf16 out) ----------------
__global__ __launch_bounds__(256) void ln_k(const float* __restrict__ x, const float* __restrict__ w,
                     const float* __restrict__ b, u16* __restrict__ out){
  __shared__ float sm[8];
  int m = blockIdx.x, t = threadIdx.x;
  const float4* xr = (const float4*)(x + (size_t)m*D_);
  float4 v = xr[t];
  float s  = v.x+v.y+v.z+v.w;
  float ss = v.x*v.x+v.y*v.y+v.z*v.z+v.w*v.w;
  for (int o=32;o;o>>=1){ s += __shfl_down(s,o,64); ss += __shfl_down(ss,o,64); }
  if ((t&63)==0){ sm[t>>6]=s; sm[4+(t>>6)]=ss; }
  __syncthreads();
  s  = sm[0]+sm[1]+sm[2]+sm[3];
  ss = sm[4]+sm[5]+sm[6]+sm[7];
  float mean = s*(1.0f/D_);
  float var  = ss*(1.0f/D_) - mean*mean;
  float rstd = rsqrtf(var + 1e-5f);
  float4 wv = ((const float4*)w)[t];
  float4 bv = ((const float4*)b)[t];
  ushort4 o4;
  o4.x = f2bf((v.x-mean)*rstd*wv.x + bv.x);
  o4.y = f2bf((v.y-mean)*rstd*wv.y + bv.y);
  o4.z = f2bf((v.z-mean)*rstd*wv.z + bv.z);
  o4.w = f2bf((v.w-mean)*rstd*wv.w + bv.w);
  ((ushort4*)(out + (size_t)m*D_))[t] = o4;
}

// ---------------- GEMM: C[M,N] = A[M,K] * W[N,K]^T (+bias)(+resid)(gelu) ----------------
// m97 structure: 128x128 tile, 4 waves, mfma_f32_16x16x32_bf16, BK=64, global_load_lds w16.
__device__ __forceinline__ void storeval(float* C, size_t i, float v){ C[i] = v; }
__device__ __forceinline__ void storeval(u16*   C, size_t i, float v){ C[i] = f2bf(v); }

template<int KIND, typename OUT_T, bool NB>
__global__ __launch_bounds__(256) void gemm_bt(const u16* __restrict__ A, const u16* __restrict__ W,
    const float* __restrict__ bias, const float* __restrict__ resid,
    OUT_T* __restrict__ C, int M, int N, int K)
{
  __shared__ u16 lA[128*64];
  __shared__ u16 lB[128*64];
  int t = threadIdx.x;
  int n0 = blockIdx.x*128, m0 = blockIdx.y*128;
  int w = t>>6, lane = t&63, quad = lane>>4, lm = lane&15;
  int wr = w>>1, wc = w&1;
  int arow = t>>3, aseg = t&7;
  f32x4 acc[4][4] = {};
  for (int k0 = 0; k0 < K; k0 += 64){
    __syncthreads();
    #pragma unroll
    for (int it=0; it<4; it++){
      gload_lds16(A + (size_t)(m0 + it*32 + arow)*K + k0 + aseg*8, &lA[it*2048 + t*8]);
      int br = n0 + it*32 + arow;
      if (NB) br = (br < N) ? br : (N-1);
      gload_lds16(W + (size_t)br*K + k0 + aseg*8, &lB[it*2048 + t*8]);
    }
    __syncthreads();
    #pragma unroll
    for (int kk=0; kk<64; kk+=32){
      bf16x8 af[4], bfr[4];
      #pragma unroll
      for (int i=0;i<4;i++) af[i]  = *(const bf16x8*)&lA[(wr*64+i*16+lm)*64 + kk + quad*8];
      #pragma unroll
      for (int j=0;j<4;j++) bfr[j] = *(const bf16x8*)&lB[(wc*64+j*16+lm)*64 + kk + quad*8];
      #pragma unroll
      for (int i=0;i<4;i++)
        #pragma unroll
        for (int j=0;j<4;j++)
          acc[i][j] = __builtin_amdgcn_mfma_f32_16x16x32_bf16(af[i], bfr[j], acc[i][j], 0,0,0);
    }
  }
  #pragma unroll
  for (int i=0;i<4;i++){
    int mb = m0 + wr*64 + i*16 + quad*4;
    #pragma unroll
    for (int j=0;j<4;j++){
      int n = n0 + wc*64 + j*16 + lm;
      if (NB && n >= N) continue;
      float bv = bias ? bias[n] : 0.0f;
      #pragma unroll
      for (int r=0;r<4;r++){
        float v = acc[i][j][r] + bv;
        int mm = mb + r;
        if (KIND==1) v += resid[(size_t)mm*N + n];
        if (KIND==2) v = 0.5f*v*(1.0f + erff(v*0.70710678118654752f));
        storeval(C, (size_t)mm*(size_t)N + n, v);
      }
    }
  }
}

// ---------------- attention: S = scale*Q K^T (causal tiles only) ----------------
__global__ __launch_bounds__(256) void qk_k(const float* __restrict__ qkv, float* __restrict__ S){
  __shared__ float lQ[64][68];
  __shared__ float lK[64][68];
  int blk = blockIdx.x;
  int qt = blk & 15, bh = blk >> 4;
  int b = bh >> 4, h = bh & 15;
  int t = threadIdx.x;
  int qi = t >> 4, ki = t & 15;
  const float* qbase = qkv + (size_t)b*T_*3072 + h*64;
  for (int idx=t; idx<4096; idx+=256){
    int r = idx>>6, d = idx&63;
    lQ[r][d] = qbase[(size_t)(qt*64+r)*3072 + d];
  }
  float* Srow = S + ((size_t)bh*T_ + qt*64)*T_;
  for (int kt=0; kt<=qt; kt++){
    __syncthreads();
    for (int idx=t; idx<4096; idx+=256){
      int r = idx>>6, d = idx&63;
      lK[r][d] = qbase[(size_t)(kt*64+r)*3072 + 1024 + d];
    }
    __syncthreads();
    float acc[4][4] = {};
    for (int d=0; d<64; d+=4){
      float4 qv[4], kv[4];
      #pragma unroll
      for (int a=0;a<4;a++) qv[a] = *(const float4*)&lQ[qi*4+a][d];
      #pragma unroll
      for (int c=0;c<4;c++) kv[c] = *(const float4*)&lK[c*16+ki][d];
      #pragma unroll
      for (int a=0;a<4;a++)
        #pragma unroll
        for (int c=0;c<4;c++)
          acc[a][c] += qv[a].x*kv[c].x + qv[a].y*kv[c].y + qv[a].z*kv[c].z + qv[a].w*kv[c].w;
    }
    #pragma unroll
    for (int a=0;a<4;a++){
      int q = qt*64 + qi*4 + a;
      #pragma unroll
      for (int c=0;c<4;c++){
        int k = kt*64 + c*16 + ki;
        Srow[(size_t)(qi*4+a)*T_ + k] = (k<=q) ? acc[a][c]*0.125f : -1e30f;
      }
    }
  }
}

// ---------------- causal-prefix softmax over rows of S ----------------
__global__ __launch_bounds__(256) void softmax_k(float* __restrict__ S){
  __shared__ float sm[8];
  int row = blockIdx.x;
  int q = row & (T_-1);
  int len = ((q>>6)+1)*64;
  float* p = S + (size_t)row*T_;
  int t = threadIdx.x;
  float v[4];
  float mx = -1e30f;
  #pragma unroll
  for (int r=0;r<4;r++){
    int i = t + r*256;
    v[r] = (i<len) ? p[i] : -1e30f;
    mx = fmaxf(mx, v[r]);
  }
  for (int o=32;o;o>>=1) mx = fmaxf(mx, __shfl_down(mx,o,64));
  if ((t&63)==0) sm[t>>6]=mx;
  __syncthreads();
  mx = fmaxf(fmaxf(sm[0],sm[1]), fmaxf(sm[2],sm[3]));
  float s = 0.f;
  #pragma unroll
  for (int r=0;r<4;r++){
    int i = t + r*256;
    v[r] = (i<len) ? expf(v[r]-mx) : 0.f;
    s += v[r];
  }
  for (int o=32;o;o>>=1) s += __shfl_down(s,o,64);
  if ((t&63)==0) sm[4+(t>>6)]=s;
  __syncthreads();
  s = sm[4]+sm[5]+sm[6]+sm[7];
  float inv = 1.0f/s;
  #pragma unroll
  for (int r=0;r<4;r++){
    int i = t + r*256;
    if (i<len) p[i] = v[r]*inv;
  }
}

// ---------------- y = P V (bf16 out into activation buffer) ----------------
__global__ __launch_bounds__(256) void pv_k(const float* __restrict__ S, const float* __restrict__ qkv,
                                            u16* __restrict__ out){
  __shared__ float lP[64][68];
  __shared__ float lVt[64][68];
  int blk = blockIdx.x;
  int qt = blk & 15, bh = blk >> 4;
  int b = bh >> 4, h = bh & 15;
  int t = threadIdx.x;
  int qi = t >> 4, ki = t & 15;
  const float* Sbase = S + ((size_t)bh*T_ + qt*64)*T_;
  const float* vbase = qkv + (size_t)b*T_*3072 + 2048 + h*64;
  float acc[4][4] = {};
  for (int kt=0; kt<=qt; kt++){
    __syncthreads();
    for (int idx=t; idx<4096; idx+=256){
      int r = idx>>6, c = idx&63;
      lP[r][c]  = Sbase[(size_t)r*T_ + kt*64 + c];
      lVt[c][r] = vbase[(size_t)(kt*64+r)*3072 + c];
    }
    __syncthreads();
    for (int k=0;k<64;k+=4){
      float4 pv[4], vv[4];
      #pragma unroll
      for (int a=0;a<4;a++) pv[a] = *(const float4*)&lP[qi*4+a][k];
      #pragma unroll
      for (int c=0;c<4;c++) vv[c] = *(const float4*)&lVt[c*16+ki][k];
      #pragma unroll
      for (int a=0;a<4;a++)
        #pragma unroll
        for (int c=0;c<4;c++)
          acc[a][c] += pv[a].x*vv[c].x + pv[a].y*vv[c].y + pv[a].z*vv[c].z + pv[a].w*vv[c].w;
    }
  }
  size_t obase = (size_t)(b*T_ + qt*64)*D_ + h*64;
  #pragma unroll
  for (int a=0;a<4;a++)
    #pragma unroll
    for (int c=0;c<4;c++)
      out[obase + (size_t)(qi*4+a)*D_ + c*16 + ki] = f2bf(acc[a][c]);
}

// ---------------- loss ----------------
__global__ __launch_bounds__(256) void loss_row_k(const float* __restrict__ logits,
                                                  const int* __restrict__ targets,
                                                  float* __restrict__ rowloss){
  __shared__ float sm[8];
  int m = blockIdx.x, t = threadIdx.x;
  const float* p = logits + (size_t)m*V_;
  float mx = -1e30f;
  for (int i=t;i<V_;i+=256) mx = fmaxf(mx, p[i]);
  for (int o=32;o;o>>=1) mx = fmaxf(mx, __shfl_down(mx,o,64));
  if ((t&63)==0) sm[t>>6]=mx;
  __syncthreads();
  mx = fmaxf(fmaxf(sm[0],sm[1]), fmaxf(sm[2],sm[3]));
  float s = 0.f;
  for (int i=t;i<V_;i+=256) s += expf(p[i]-mx);
  for (int o=32;o;o>>=1) s += __shfl_down(s,o,64);
  if ((t&63)==0) sm[4+(t>>6)]=s;
  __syncthreads();
  if (t==0){
    s = sm[4]+sm[5]+sm[6]+sm[7];
    rowloss[m] = logf(s) + mx - p[targets[m]];
  }
}

__global__ void loss_reduce_k(const float* __restrict__ rowloss, float* __restrict__ out){
  __shared__ float sm[4];
  int t = threadIdx.x;
  float s = 0.f;
  for (int i=t;i<M_;i+=256) s += rowloss[i];
  for (int o=32;o;o>>=1) s += __shfl_down(s,o,64);
  if ((t&63)==0) sm[t>>6]=s;
  __syncthreads();
  if (t==0) out[0] = (sm[0]+sm[1]+sm[2]+sm[3])*(1.0f/M_);
}

// ---------------- launch ----------------
extern "C" void kernel_launch(void* const* d_in, const int* in_sizes, int n_in,
                              void* d_out, int out_size, void* d_ws, size_t ws_size,
                              hipStream_t stream) {
  const int*   idx     = (const int*)d_in[0];
  const int*   targets = (const int*)d_in[1];
  const float* wte     = (const float*)d_in[2];
  const float* wpe     = (const float*)d_in[3];
  const float* ln1_w   = (const float*)d_in[4];
  const float* ln1_b   = (const float*)d_in[5];
  const float* attn_w  = (const float*)d_in[6];
  const float* attn_b  = (const float*)d_in[7];
  const float* proj_w  = (const float*)d_in[8];
  const float* proj_b  = (const float*)d_in[9];
  const float* ln2_w   = (const float*)d_in[10];
  const float* ln2_b   = (const float*)d_in[11];
  const float* fc_w    = (const float*)d_in[12];
  const float* fc_b    = (const float*)d_in[13];
  const float* fcp_w   = (const float*)d_in[14];
  const float* fcp_b   = (const float*)d_in[15];
  const float* lnf_w   = (const float*)d_in[16];
  const float* lnf_b   = (const float*)d_in[17];

  char* ws = (char*)d_ws;
  size_t off = 0;
  auto alloc = [&](size_t bytes)->void*{ void* p = ws + off; off += (bytes + 255) & ~(size_t)255; return p; };
  u16*   wte_bf  = (u16*)  alloc((size_t)V_*D_*2);
  u16*   aw_bf   = (u16*)  alloc((size_t)L_*3*D_*D_*2);
  u16*   pw_bf   = (u16*)  alloc((size_t)L_*D_*D_*2);
  u16*   fw_bf   = (u16*)  alloc((size_t)L_*4*D_*D_*2);
  u16*   fpw_bf  = (u16*)  alloc((size_t)L_*D_*4*D_*2);
  float* xb      = (float*)alloc((size_t)M_*D_*4);
  u16*   actA    = (u16*)  alloc((size_t)M_*4*D_*2);
  u16*   actB    = (u16*)  alloc((size_t)M_*4*D_*2);
  float* qkvb    = (float*)alloc((size_t)M_*3*D_*4);
  float* scores  = (float*)alloc((size_t)B_*H_*T_*T_*4);
  float* rowloss = (float*)alloc((size_t)M_*4);
  (void)ws_size; (void)in_sizes; (void)n_in; (void)out_size;

  auto cvt = [&](const float* in, u16* out, size_t n){
    int n4 = (int)(n/4);
    cvt_bf16x4<<<dim3((n4+255)/256), dim3(256), 0, stream>>>((const float4*)in, (ushort4*)out, n4);
  };
  cvt(wte,    wte_bf, (size_t)V_*D_);
  cvt(attn_w, aw_bf,  (size_t)L_*3*D_*D_);
  cvt(proj_w, pw_bf,  (size_t)L_*D_*D_);
  cvt(fc_w,   fw_bf,  (size_t)L_*4*D_*D_);
  cvt(fcp_w,  fpw_bf, (size_t)L_*D_*4*D_);

  embed_k<<<M_, 256, 0, stream>>>(idx, wte, wpe, xb);

  for (int l=0; l<L_; l++){
    ln_k<<<M_, 256, 0, stream>>>(xb, ln1_w + l*D_, ln1_b + l*D_, actA);
    gemm_bt<0,float,false><<<dim3(24,16), 256, 0, stream>>>(
        actA, aw_bf + (size_t)l*3*D_*D_, attn_b + l*3*D_, nullptr, qkvb, M_, 3*D_, D_);
    qk_k<<<B_*H_*16, 256, 0, stream>>>(qkvb, scores);
    softmax_k<<<B_*H_*T_, 256, 0, stream>>>(scores);
    pv_k<<<B_*H_*16, 256, 0, stream>>>(scores, qkvb, actA);
    gemm_bt<1,float,false><<<dim3(8,16), 256, 0, stream>>>(
        actA, pw_bf + (size_t)l*D_*D_, proj_b + l*D_, xb, xb, M_, D_, D_);
    ln_k<<<M_, 256, 0, stream>>>(xb, ln2_w + l*D_, ln2_b + l*D_, actA);
    gemm_bt<2,u16,false><<<dim3(32,16), 256, 0, stream>>>(
        actA, fw_bf + (size_t)l*4*D_*D_, fc_b + l*4*D_, nullptr, actB, M_, 4*D_, D_);
    gemm_bt<1,float,false><<<dim3(8,16), 256, 0, stream>>>(
        actB, fpw_bf + (size_t)l*D_*4*D_, fcp_b + l*D_, xb, xb, M_, D_, 4*D_);
  }

  ln_k<<<M_, 256, 0, stream>>>(xb, lnf_w, lnf_b, actA);
  float* logits = (float*)d_out;
  gemm_bt<0,float,true><<<dim3((V_+127)/128, 16), 256, 0, stream>>>(
      actA, wte_bf, nullptr, nullptr, logits, M_, V_, D_);
  loss_row_k<<<M_, 256, 0, stream>>>(logits, targets, rowloss);
  loss_reduce_k<<<1, 256, 0, stream>>>(rowloss, logits + (size_t)M_*V_);
}